// Round 1
// baseline (179.915 us; speedup 1.0000x reference)
//
#include <hip/hip_runtime.h>

// Problem constants (mirrors reference)
#define NI    32              // batch
#define HH    1024
#define WW    1024
#define BHW   16              // pool window
#define BS    14              // block stride
#define NBH   73              // block count h
#define NBW   73              // block count w
#define NCHUNK (NI * NBH)     // 2336 block-rows
#define TOTAL  (NI * NBH * NBW) // 170528
#define ROWDW  (3 * NBW)      // 219 output dwords per chunk

struct umask2 { unsigned long long x, y; };

__device__ __forceinline__ float4 max4(float4 a, float4 b) {
    return make_float4(fmaxf(a.x, b.x), fmaxf(a.y, b.y),
                       fmaxf(a.z, b.z), fmaxf(a.w, b.w));
}

// Speculative "all 73 windows active" enumeration write for one chunk:
// out rows [chunk*73, chunk*73+73) = (n, by, 0..72). 219 consecutive dword
// stores by threads 0..218 — coalesced. This IS the final answer whenever
// the global deficit count is 0 (P(otherwise) ~ 3e-7 on uniform data).
__device__ __forceinline__ void write_full_row(int* __restrict__ out,
                                               int chunk, int n, int by, int tid) {
    if (tid < ROWDW) {
        const int q = tid / 3;            // bx
        const int comp = tid - 3 * q;     // 0:n 1:by 2:bx
        out[(size_t)chunk * ROWDW + tid] = (comp == 0) ? n : ((comp == 1) ? by : q);
    }
}

// ---------------------------------------------------------------------------
// Kernel 1: one workgroup per (n, by) block-row.
//
// Phase 1 (common, ~96.4%): load 6 window rows as independent float4 loads
// (single HBM round-trip), then ONE conservative all-windows-hit test:
// per-lane "colmax4 > 0.9" ballots give a 256-bit map (1 bit = 4 cols);
// window bx (cols [14bx-1, 14bx+14]) tests only the 3-4 ballot bits FULLY
// inside the window (>=12 interior cols) — a set bit proves window-max > 0.9
// with no false positives. P(some window unproven | 6 rows, uniform data)
// ~ 73 * 0.9^72 ~ 3.6%. If all 73 prove: emit all-ones mask + speculative
// enumeration, done — exactly one load round + 2 barrier ops.
//
// Phase 2 (rare): load the remaining rows, exact colmax + horizontal max.
// If the exact count != 73, bump the global deficit counter so kernel 2
// takes its exact (original, verified) path.
__global__ __launch_bounds__(256, 8) void pool_kernel(const float* __restrict__ mask,
                                                      umask2* __restrict__ masks,
                                                      int* __restrict__ counts,
                                                      int* __restrict__ deficit,
                                                      int* __restrict__ out) {
    const int chunk = blockIdx.x;         // n*NBH + by
    const int n  = chunk / NBH;
    const int by = chunk % NBH;
    const int tid  = threadIdx.x;
    const int lane = tid & 63;
    const int wave = tid >> 6;

    __shared__ float colmax[WW];
    __shared__ unsigned long long wb[4];
    __shared__ unsigned long long sm0, sm1;

    const int r0 = by * BS - 1;           // padded window start (pad=1)
    const int rs = max(r0, 0);            // only by==0 clips; bottom never does
    const int nr = (by > 0) ? 16 : 15;    // valid rows in window
    const float* p = mask + (size_t)n * HH * WW + (size_t)rs * WW + tid * 4;

    // ---- phase 1: 6 independent row loads, full ILP ----
    const float4 a0 = *(const float4*)(p + 0 * (size_t)WW);
    const float4 a1 = *(const float4*)(p + 1 * (size_t)WW);
    const float4 a2 = *(const float4*)(p + 2 * (size_t)WW);
    const float4 a3 = *(const float4*)(p + 3 * (size_t)WW);
    const float4 a4 = *(const float4*)(p + 4 * (size_t)WW);
    const float4 a5 = *(const float4*)(p + 5 * (size_t)WW);
    float4 m = max4(max4(max4(a0, a1), max4(a2, a3)), max4(a4, a5));

    const float mm = fmaxf(fmaxf(m.x, m.y), fmaxf(m.z, m.w));
    const unsigned long long bal = __ballot(mm > 0.9f);
    if (lane == 0) wb[wave] = bal;
    __syncthreads();

    bool whit = true;                     // tid >= 73 -> vacuously true
    if (tid < NBW) {
        const int c0 = tid * BS;
        const int lo = (c0 + 2) >> 2;     // first bit fully inside window
        const int hi = (c0 + 11) >> 2;    // last bit fully inside window
        const int w0 = lo >> 6, sh = lo & 63;
        unsigned long long bits = wb[w0] >> sh;
        if (w0 < 3 && sh) bits |= wb[w0 + 1] << (64 - sh);
        const int nb = hi - lo + 1;       // 3 or 4
        whit = (bits & ((1ull << nb) - 1ull)) != 0ull;
    }
    const bool done = __syncthreads_and((int)whit) != 0;

    if (done) {                           // exact: every window proved > 0.9
        if (tid == 0) {
            umask2 mk; mk.x = ~0ull; mk.y = (1ull << (NBW - 64)) - 1ull;
            masks[chunk] = mk;
            counts[chunk] = NBW;
        }
        write_full_row(out, chunk, n, by, tid);
        return;                           // block-uniform
    }

    // ---- phase 2 (rare): accumulate remaining rows, exact fallback ----
    for (int r = 6; r < nr; ++r)
        m = max4(m, *(const float4*)(p + (size_t)r * WW));

    const int c = tid * 4;
    colmax[c + 0] = m.x;
    colmax[c + 1] = m.y;
    colmax[c + 2] = m.z;
    colmax[c + 3] = m.w;
    __syncthreads();

    int f = 0;
    if (tid < NBW) {
        const int c0 = tid * BS - 1;
        float mx = colmax[max(c0, 0)];    // dc=0 clamped; dc>=1 always >= 0
        #pragma unroll
        for (int dc = 1; dc < BHW; ++dc) mx = fmaxf(mx, colmax[c0 + dc]);
        f = (mx > 0.9f) ? 1 : 0;
    }
    const unsigned long long b = __ballot(f);
    if (wave == 0 && lane == 0) sm0 = b;  // bits for bx 0..63
    if (wave == 1 && lane == 0) sm1 = b;  // bits for bx 64..72
    __syncthreads();

    const int cnt = __popcll(sm0) + __popcll(sm1);
    if (tid == 0) {
        umask2 mk; mk.x = sm0; mk.y = sm1;
        masks[chunk] = mk;
        counts[chunk] = cnt;
        if (cnt != NBW) atomicAdd(deficit, 1);   // device-scope, kernel 2 sees it
    }
    if (cnt == NBW)                        // conservative test missed, but full:
        write_full_row(out, chunk, n, by, tid);  // speculative row still valid
}

// ---------------------------------------------------------------------------
// Kernel 2: exact path only. If deficit == 0 (the always case), every chunk
// already wrote its enumeration at chunk*73 and there is no -1 tail
// (grand total == TOTAL) — nothing to do. Otherwise run the original
// (verified) fused exclusive-scan + stable scatter + -1 tail fill, which
// writes EVERY output row exactly once, overwriting any speculative rows.
__global__ __launch_bounds__(128) void scatter_kernel(const umask2* __restrict__ masks,
                                                      const int* __restrict__ counts,
                                                      const int* __restrict__ deficit,
                                                      int* __restrict__ out) {
    if (*deficit == 0) return;            // block-uniform, L2-broadcast load

    const int chunk = blockIdx.x;
    const int n  = chunk / NBH;
    const int by = chunk % NBH;
    const int tid  = threadIdx.x;
    const int lane = tid & 63;
    const int wave = tid >> 6;

    __shared__ int wsum[2];

    // global exclusive prefix of counts
    int partial = 0;
    for (int i = tid; i < chunk; i += 128) partial += counts[i];
    #pragma unroll
    for (int off = 32; off > 0; off >>= 1) partial += __shfl_down(partial, off, 64);
    if (lane == 0) wsum[wave] = partial;

    const umask2 m = masks[chunk];        // broadcast load, L2-hot
    __syncthreads();
    const int e = wsum[0] + wsum[1];
    const int c = __popcll(m.x) + __popcll(m.y);

    // stable scatter of active triples
    if (tid < NBW) {
        int f, prefix;
        if (wave == 0) {                  // bx 0..63 (wave-uniform branch)
            f = (int)((m.x >> tid) & 1ull);
            prefix = __popcll(m.x & ((1ull << tid) - 1ull));
        } else {                          // bx 64..72
            const int t = tid - 64;
            f = (int)((m.y >> t) & 1ull);
            prefix = __popcll(m.x) + __popcll(m.y & ((1ull << t) - 1ull));
        }
        if (f) {
            const int pos = e + prefix;
            out[3 * pos + 0] = n;
            out[3 * pos + 1] = by;
            out[3 * pos + 2] = tid;
        }
    }

    // -1 slack fill: S_incl(i) = (i+1)*NBW - (e_i + c_i); block i fills
    // rows [TOTAL - S_incl, TOTAL - S_incl + (NBW - c_i)) — exact tiling of
    // [grand_total, TOTAL); every output row written exactly once.
    const int slack = NBW - c;
    if (slack > 0) {
        const int s_incl = (chunk + 1) * NBW - (e + c);
        const int base3 = 3 * (TOTAL - s_incl);
        const int n3 = 3 * slack;
        for (int i = tid; i < n3; i += 128) out[base3 + i] = -1;
    }
}

// ---------------------------------------------------------------------------
extern "C" void kernel_launch(void* const* d_in, const int* in_sizes, int n_in,
                              void* d_out, int out_size, void* d_ws, size_t ws_size,
                              hipStream_t stream) {
    const float* mask = (const float*)d_in[0];
    int* out = (int*)d_out;

    // workspace layout: [masks: 2336 x 16B][counts: 2336 x 4B][deficit: 4B]
    umask2* masks = (umask2*)d_ws;
    int* counts = (int*)(masks + NCHUNK);
    int* deficit = counts + NCHUNK;

    hipMemsetAsync(deficit, 0, sizeof(int), stream);  // graph-capturable memset node
    pool_kernel<<<NCHUNK, 256, 0, stream>>>(mask, masks, counts, deficit, out);
    scatter_kernel<<<NCHUNK, 128, 0, stream>>>(masks, counts, deficit, out);
}